// Round 1
// 824.168 us; speedup vs baseline: 1.0285x; 1.0285x over previous
//
#include <hip/hip_runtime.h>
#include <cstdint>
#include <cstddef>

#define DEVI __device__ __forceinline__

constexpr int N_TOK = 4096, DIM = 1024, HID = 4096, NE = 8;
constexpr int NKR = N_TOK * 2;   // total routed rows (every token picks exactly 2 experts)

typedef __attribute__((ext_vector_type(8))) short short8;
typedef __attribute__((ext_vector_type(4))) float f32x4;

DEVI ushort f2bf(float f) {
  union { float f; uint32_t u; } v; v.f = f;
  uint32_t r = v.u + 0x7FFFu + ((v.u >> 16) & 1u);   // round-to-nearest-even
  return (ushort)(r >> 16);
}

DEVI float gelu_t(float x) {
  // tanh-approx GELU, matches jax.nn.gelu(approximate=True)
  float t = 0.7978845608028654f * (x + 0.044715f * x * x * x);
  t = fminf(fmaxf(t, -15.f), 15.f);
  float e = __expf(2.f * t);
  return 0.5f * x * (1.f + (e - 1.f) / (e + 1.f));
}

// Direct global->LDS DMA, 16B/lane. LDS dest is WAVE-UNIFORM base + lane*16
// (linear; no padding allowed). Global src is per-lane.
DEVI void gload_lds16(const ushort* g, ushort* l) {
  __builtin_amdgcn_global_load_lds(
      (const __attribute__((address_space(1))) void*)g,
      (__attribute__((address_space(3))) void*)l, 16, 0, 0);
}

__global__ void zero_out_kernel(float* __restrict__ out, int n) {
  int i = blockIdx.x * 256 + threadIdx.x;
  if (i < n) out[i] = 0.f;
}

// ---------------- x fp32 -> bf16 ----------------
__global__ void convert_x_kernel(const float* __restrict__ x, ushort* __restrict__ xbf) {
  int i = (blockIdx.x * 256 + threadIdx.x) * 4;
  float4 v = *(const float4*)(x + i);
  ushort4 o;
  o.x = f2bf(v.x); o.y = f2bf(v.y); o.z = f2bf(v.z); o.w = f2bf(v.w);
  *(ushort4*)(xbf + i) = o;
}

// ---------------- transpose [E][R][C] fp32 -> [E][C][R] bf16 ----------------
template<int R, int C>
__global__ void transpose_bf16(const float* __restrict__ src, ushort* __restrict__ dst) {
  __shared__ ushort t[64][68];          // 68: keep ushort4 rows 8B-aligned, break bank stride
  int e = blockIdx.z;
  const float* s = src + (size_t)e * R * C;
  ushort* d = dst + (size_t)e * R * C;
  int r0 = blockIdx.y * 64, c0 = blockIdx.x * 64;
  int lr = threadIdx.x >> 4;            // 0..15
  int lc = (threadIdx.x & 15) * 4;      // 0..60
#pragma unroll
  for (int i = 0; i < 4; ++i) {
    int r = lr + i * 16;
    float4 v = *(const float4*)(s + (size_t)(r0 + r) * C + c0 + lc);
    t[lc + 0][r] = f2bf(v.x);
    t[lc + 1][r] = f2bf(v.y);
    t[lc + 2][r] = f2bf(v.z);
    t[lc + 3][r] = f2bf(v.w);
  }
  __syncthreads();
#pragma unroll
  for (int i = 0; i < 4; ++i) {
    int c = lr + i * 16;                // output row = original column
    ushort4 o = *(const ushort4*)&t[c][lc];
    *(ushort4*)(d + (size_t)(c0 + c) * R + r0 + lc) = o;
  }
}

// ---------------- gating: logits -> softmax -> top2 (fp64 for ref-stable top-k) ----------------
__global__ void gate_kernel(const float* __restrict__ x, const float* __restrict__ gw,
                            const float* __restrict__ gb,
                            int* __restrict__ topi, float* __restrict__ topw,
                            int* __restrict__ counts) {
  int n = blockIdx.x;
  int lane = threadIdx.x;               // block = 1 wave = 64 lanes
  double p[NE];
#pragma unroll
  for (int e = 0; e < NE; ++e) p[e] = 0.0;
  const float* xr = x + (size_t)n * DIM;
  for (int d = lane; d < DIM; d += 64) {
    float xv = xr[d];
    const float* g = gw + (size_t)d * NE;
#pragma unroll
    for (int e = 0; e < NE; ++e) p[e] += (double)xv * (double)g[e];
  }
#pragma unroll
  for (int e = 0; e < NE; ++e) {
#pragma unroll
    for (int s = 32; s > 0; s >>= 1) p[e] += __shfl_down(p[e], s);
  }
  if (lane == 0) {
    double m = -1e300;
#pragma unroll
    for (int e = 0; e < NE; ++e) { p[e] += (double)gb[e]; if (p[e] > m) m = p[e]; }
    double s = 0.0, ex[NE];
#pragma unroll
    for (int e = 0; e < NE; ++e) { ex[e] = exp(p[e] - m); s += ex[e]; }
    double inv = 1.0 / s;
    int e0 = 0, e1 = 0; double v0 = -1.0, v1 = -1.0;
#pragma unroll
    for (int e = 0; e < NE; ++e) {
      double pe = ex[e] * inv;
      if (pe > v0)      { v1 = v0; e1 = e0; v0 = pe; e0 = e; }
      else if (pe > v1) { v1 = pe; e1 = e; }
    }
    topi[n * 2] = e0; topi[n * 2 + 1] = e1;
    topw[n * 2] = (float)v0; topw[n * 2 + 1] = (float)v1;
    atomicAdd(&counts[e0], 1);
    atomicAdd(&counts[e1], 1);
  }
}

__global__ void prefix_kernel(const int* __restrict__ counts, int* __restrict__ offs) {
  if (threadIdx.x == 0) {
    int s = 0;
    for (int e = 0; e < NE; ++e) { offs[e] = s; s += counts[e]; }
  }
}

__global__ void scatter_kernel(const int* __restrict__ topi, const float* __restrict__ topw,
                               const int* __restrict__ offs, int* __restrict__ fill,
                               int* __restrict__ tok, float* __restrict__ wgt) {
  int n = blockIdx.x * blockDim.x + threadIdx.x;
  if (n >= N_TOK) return;
#pragma unroll
  for (int k = 0; k < 2; ++k) {
    int e = topi[n * 2 + k];
    int pos = atomicAdd(&fill[e], 1);
    int g = offs[e] + pos;
    tok[g] = n;
    wgt[g] = topw[n * 2 + k];
  }
}

// ---------------- routed GEMM, 128x128 tile, BK=64, mfma 16x16x32 bf16 ----------------
// m97 structure: global_load_lds(16B) direct-to-LDS staging, linear LDS [128][64],
// 2-barrier K-loop, 4 waves each computing a 64x64 quadrant via 4x4 16x16 frags.
// FIRST: hbuf[g][h] = gelu( gather(x)[g] @ Wt[e]^T + b1 )        (K = DIM)
// !FIRST: out[tok[g]][d] += wgt[g] * ( hbuf[g] @ Wt[e]^T + b2 )  (K = HID)
template<int K, bool FIRST>
__global__ __launch_bounds__(256) void moe_gemm(
    const ushort* __restrict__ A,     // FIRST: xbf [N_TOK][DIM] ; else hbuf [NKR][HID]
    const ushort* __restrict__ B,     // FIRST: W1t [E][HID][DIM]; else W2t [E][DIM][HID]
    const float* __restrict__ bias,   // FIRST: b1 [E][HID]      ; else b2 [E][DIM]
    const int* __restrict__ tok, const float* __restrict__ wgt,
    const int* __restrict__ offs, const int* __restrict__ counts,
    ushort* __restrict__ hbuf, float* __restrict__ out)
{
  constexpr int NCOL = FIRST ? HID : DIM;
  // Linear layout [128][64] — REQUIRED by global_load_lds (wave-uniform base +
  // lane*16B, contiguous). No pad: bank conflicts on ds_read are hidden at this
  // 2-phase structure (critical path = stage+barrier, T2 regime gate).
  __shared__ ushort Asm[128 * 64];
  __shared__ ushort Bsm[128 * 64];

  const int e = blockIdx.z;
  const int cnt = counts[e];
  const int mbase = blockIdx.y * 128;
  if (mbase >= cnt) return;           // early-exit tiles beyond this expert's row count
  const int off = offs[e];
  const int nbase = blockIdx.x * 128;
  int rv = cnt - mbase; if (rv > 128) rv = 128;

  const int tid = threadIdx.x;
  const int lane = tid & 63, wave = tid >> 6;
  const int sr = tid >> 3;            // staging row 0..31 (+32 per iter)
  const int sc = (tid & 7) * 8;       // staging k-offset (8 bf16 = 16B)

  // Per-lane global row pointers (gather for A). OOB rows clamp to a valid row:
  // their acc rows are garbage but the epilogue skips mm >= rv, and MFMA output
  // rows depend only on their own A row, so no contamination of valid rows.
  const ushort* arow[4];
  const ushort* brow[4];
  const ushort* Be = B + (size_t)e * ((size_t)HID * DIM) + (size_t)nbase * K;
#pragma unroll
  for (int i = 0; i < 4; ++i) {
    int r = sr + 32 * i;
    int rc = r < rv ? r : rv - 1;
    int g = off + mbase + rc;
    long t = FIRST ? (long)tok[g] : (long)g;
    arow[i] = A + t * (long)K + sc;
    brow[i] = Be + (size_t)r * K + sc;   // B rows always valid (NCOL multiple of 128)
  }

  f32x4 acc[4][4];
#pragma unroll
  for (int a = 0; a < 4; ++a)
#pragma unroll
    for (int b = 0; b < 4; ++b) acc[a][b] = (f32x4)0.f;

  const int quad = lane >> 4, lrow = lane & 15;
  const int wm = (wave >> 1) * 64, wn = (wave & 1) * 64;

  for (int k0 = 0; k0 < K; k0 += 64) {
    // stage: 8 global_load_lds_dwordx4 per thread-block iteration slice.
    // Wave w, iter i covers rows [i*32 + w*8, i*32 + w*8 + 8) — lane l writes
    // LDS base + l*16B = row (base + l>>3), shorts (l&7)*8, matching arow/brow.
#pragma unroll
    for (int i = 0; i < 4; ++i) {
      gload_lds16(arow[i] + k0, &Asm[(i * 32 + wave * 8) * 64]);
      gload_lds16(brow[i] + k0, &Bsm[(i * 32 + wave * 8) * 64]);
    }
    __syncthreads();                 // drains vmcnt (compiler-inserted), LDS ready
#pragma unroll
    for (int ks = 0; ks < 2; ++ks) {
      short8 af[4], bf[4];
#pragma unroll
      for (int mt = 0; mt < 4; ++mt)
        af[mt] = *(const short8*)&Asm[(wm + mt * 16 + lrow) * 64 + ks * 32 + quad * 8];
#pragma unroll
      for (int nt = 0; nt < 4; ++nt)
        bf[nt] = *(const short8*)&Bsm[(wn + nt * 16 + lrow) * 64 + ks * 32 + quad * 8];
#pragma unroll
      for (int mt = 0; mt < 4; ++mt)
#pragma unroll
        for (int nt = 0; nt < 4; ++nt)
          acc[mt][nt] = __builtin_amdgcn_mfma_f32_16x16x32_bf16(af[mt], bf[nt], acc[mt][nt], 0, 0, 0);
    }
    __syncthreads();
  }

  // epilogue: C/D layout col = lane&15, row = quad*4 + reg
  if (FIRST) {
#pragma unroll
    for (int mt = 0; mt < 4; ++mt) {
#pragma unroll
      for (int i = 0; i < 4; ++i) {
        int mm = wm + mt * 16 + quad * 4 + i;
        if (mm >= rv) continue;
        size_t g = (size_t)(off + mbase + mm);
#pragma unroll
        for (int nt = 0; nt < 4; ++nt) {
          int col = nbase + wn + nt * 16 + lrow;
          float v = gelu_t(acc[mt][nt][i] + bias[e * NCOL + col]);
          hbuf[g * HID + col] = f2bf(v);
        }
      }
    }
  } else {
#pragma unroll
    for (int mt = 0; mt < 4; ++mt) {
#pragma unroll
      for (int i = 0; i < 4; ++i) {
        int mm = wm + mt * 16 + quad * 4 + i;
        if (mm >= rv) continue;
        int g = off + mbase + mm;
        long t = tok[g];
        float w = wgt[g];
#pragma unroll
        for (int nt = 0; nt < 4; ++nt) {
          int col = nbase + wn + nt * 16 + lrow;
          float v = w * (acc[mt][nt][i] + bias[e * NCOL + col]);
          atomicAdd(out + t * DIM + col, v);
        }
      }
    }
  }
}

extern "C" void kernel_launch(void* const* d_in, const int* in_sizes, int n_in,
                              void* d_out, int out_size, void* d_ws, size_t ws_size,
                              hipStream_t stream) {
  const float* x  = (const float*)d_in[0];
  const float* gw = (const float*)d_in[1];
  const float* gb = (const float*)d_in[2];
  const float* W1 = (const float*)d_in[3];
  const float* b1 = (const float*)d_in[4];
  const float* W2 = (const float*)d_in[5];
  const float* b2 = (const float*)d_in[6];
  float* out = (float*)d_out;

  // ---- workspace layout (small buffers first, big buffers after) ----
  char* ws = (char*)d_ws;
  size_t o = 0;
  auto alloc = [&](size_t b) { char* p = ws + o; o = (o + b + 255) & ~(size_t)255; return p; };
  int*    tok  = (int*)alloc(NKR * 4);
  float*  wgt  = (float*)alloc(NKR * 4);
  int*    topi = (int*)alloc(N_TOK * 2 * 4);
  float*  topw = (float*)alloc(N_TOK * 2 * 4);
  int*    counts = (int*)alloc(2 * NE * 4);
  int*    fill = counts + NE;
  int*    offs = (int*)alloc(NE * 4);
  ushort* xbf  = (ushort*)alloc((size_t)N_TOK * DIM * 2);        //   8 MB
  ushort* hbuf = (ushort*)alloc((size_t)NKR * HID * 2);          //  64 MB
  ushort* Wt   = (ushort*)alloc((size_t)NE * HID * DIM * 2);     //  64 MB (shared: W1t then W2t)
  size_t need = o;

  // Guard: never write past d_ws. If scratch is too small, emit zeros (clean
  // absmax failure instead of a container-killing OOB fault — diagnostic).
  zero_out_kernel<<<(out_size + 255) / 256, 256, 0, stream>>>(out, out_size);
  if (ws_size < need) return;

  hipMemsetAsync(counts, 0, 2 * NE * 4, stream);

  convert_x_kernel<<<(N_TOK * DIM / 4) / 256, 256, 0, stream>>>(x, xbf);
  gate_kernel<<<N_TOK, 64, 0, stream>>>(x, gw, gb, topi, topw, counts);
  prefix_kernel<<<1, 64, 0, stream>>>(counts, offs);
  scatter_kernel<<<(N_TOK + 255) / 256, 256, 0, stream>>>(topi, topw, offs, fill, tok, wgt);

  // ---- expert MLP layer 1: Wt <- W1^T, hbuf = gelu(gather(x) @ W1 + b1) ----
  transpose_bf16<DIM, HID><<<dim3(HID / 64, DIM / 64, NE), 256, 0, stream>>>(W1, Wt);
  moe_gemm<DIM, true ><<<dim3(HID / 128, 32, NE), 256, 0, stream>>>(
      xbf, Wt, b1, tok, wgt, offs, counts, hbuf, out);

  // ---- expert MLP layer 2: Wt <- W2^T (reuse), out += wgt * (hbuf @ W2 + b2) ----
  transpose_bf16<HID, DIM><<<dim3(DIM / 64, HID / 64, NE), 256, 0, stream>>>(W2, Wt);
  moe_gemm<HID, false><<<dim3(DIM / 128, 32, NE), 256, 0, stream>>>(
      hbuf, Wt, b2, tok, wgt, offs, counts, hbuf, out);
}